// Round 5
// baseline (6015.717 us; speedup 1.0000x reference)
//
#include <hip/hip_runtime.h>
#include <math.h>

// (P, C, NX, NY, NT) = (2, 1, 128, 128, 8), T = 128
#define NP     2
#define NXD    128
#define NYD    128
#define NTD    8
#define PLANE  (NYD * NTD)        // 1024 sites per x-plane
#define NSITES (NP * NXD * PLANE) // 262144
#define NBLK   (NP * NXD)         // 256 blocks, one x-plane each
#define NWAVE  16                 // waves per block
#define TSTEPS 128
#define DEPTH  4                  // slot depth for cross-block buffer

#define AGENT __HIP_MEMORY_SCOPE_AGENT

union pkT { float f[2]; unsigned long long u; };

__global__ __launch_bounds__(1024, 4) void pdhg_persist(
    const float* __restrict__ x,
    const float* __restrict__ lam,
    const float* __restrict__ tau_p,
    const float* __restrict__ sigma_p,
    const float* __restrict__ theta_p,
    unsigned long long* __restrict__ pk_g,  // DEPTH * NSITES packed {xbar,q0}
    unsigned* __restrict__ flags,           // (NBLK*NWAVE) flags, 32 uints (128B) apart
    float* __restrict__ out)
{
    __shared__ float xb_lds[2][PLANE];
    __shared__ float q1_lds[2][PLANE];
    __shared__ float q2_lds[2][PLANE];

    const int b   = blockIdx.x;        // plane = p*128 + ix
    const int tid = threadIdx.x;       // y*8 + t
    const int wv  = tid >> 6;          // wave id 0..15
    const int pp  = b >> 7;
    const int ix  = b & 127;
    const int idx = b * PLANE + tid;

    const int b_xp = (pp << 7) + ((ix + 1) & 127);
    const int b_xm = (pp << 7) + ((ix + 127) & 127);
    const int g_xp = b_xp * PLANE + tid;
    const int g_xm = b_xm * PLANE + tid;

    const int t = tid & 7;
    const int l_yp = (tid + 8) & (PLANE - 1);
    const int l_ym = (tid - 8) & (PLANE - 1);
    const int l_tp = (t == 7) ? tid - 7 : tid + 1;
    const int l_tm = (t == 0) ? tid + 7 : tid - 1;

    // per-(block,wave) flags, 128B apart: writer = 1 lane, pollers = 2 waves
    unsigned* flag_self = flags + (b    * NWAVE + wv) * 32;
    unsigned* flag_p    = flags + (b_xp * NWAVE + wv) * 32;
    unsigned* flag_m    = flags + (b_xm * NWAVE + wv) * 32;

    const float L = 3.605551275463989f;  // sqrt(13)
    const float s_sig = (1.f / (1.f + __expf(-sigma_p[0]))) / L;
    const float s_tau = (1.f / (1.f + __expf(-tau_p[0]))) / L;
    const float s_th  =  1.f / (1.f + __expf(-theta_p[0]));
    const float inv1s = 1.f / (1.f + s_sig);

    const float xn   = x[idx];
    const float lamc = lam[idx];
    const float lxm  = lam[g_xm];
    const float lym  = lam[b * PLANE + l_ym];
    const float ltm  = lam[b * PLANE + l_tm];

    // register-resident state for all 128 steps
    float x0v = xn, pv = xn, q0v = 0.f, q1v = 0.f, q2v = 0.f, xbv = xn;

    auto step_math = [&](float xbxp, float xbxm, float xbyp, float xbym,
                         float xbtp, float xbtm, float q0xm, float q1ym, float q2tm) {
        const float p_new = (pv + s_sig * (xbv - xn)) * inv1s;
        const float q0n = fmaxf(-lamc, fminf(lamc, q0v + s_sig * (xbxp - xbv)));
        const float q1n = fmaxf(-lamc, fminf(lamc, q1v + s_sig * (xbyp - xbv)));
        const float q2n = fmaxf(-lamc, fminf(lamc, q2v + s_sig * (xbtp - xbv)));
        // backward neighbors' new q (redundant compute -> single phase per step)
        const float q0nm = fmaxf(-lxm, fminf(lxm, q0xm + s_sig * (xbv - xbxm)));
        const float q1nm = fmaxf(-lym, fminf(lym, q1ym + s_sig * (xbv - xbym)));
        const float q2nm = fmaxf(-ltm, fminf(ltm, q2tm + s_sig * (xbv - xbtm)));
        const float div = (q0nm - q0n) + (q1nm - q1n) + (q2nm - q2n);
        const float x1 = x0v - s_tau * (p_new + div);
        const float xb_new = x1 + s_th * (x1 - x0v);
        pv = p_new; q0v = q0n; q1v = q1n; q2v = q2n;
        x0v = x1; xbv = xb_new;
    };

    // publish step-s data; wave-autonomous flag (no block barrier in the chain)
    auto publish = [&](int s) {
        pkT pk; pk.f[0] = xbv; pk.f[1] = q0v;
        __hip_atomic_store(&pk_g[(size_t)(s & (DEPTH - 1)) * NSITES + idx],
                           pk.u, __ATOMIC_RELAXED, AGENT);
        if ((tid & 63) == 0) {
            // release drains this wave's vmcnt (its lanes' stores are at LLC)
            __hip_atomic_store(flag_self, (unsigned)(s + 1), __ATOMIC_RELEASE, AGENT);
        }
    };

    // wait for neighbor waves to have published step s, then load halo
    auto waitload = [&](int s, pkT& pkp, pkT& pkm) {
        const unsigned need = (unsigned)(s + 1);
        while (__hip_atomic_load(flag_p, __ATOMIC_RELAXED, AGENT) < need ||
               __hip_atomic_load(flag_m, __ATOMIC_RELAXED, AGENT) < need) {
        }
        __atomic_signal_fence(__ATOMIC_ACQUIRE);  // no compiler hoist of data loads
        const size_t r3 = (size_t)(s & (DEPTH - 1)) * NSITES;
        pkp.u = __hip_atomic_load(&pk_g[r3 + g_xp], __ATOMIC_RELAXED, AGENT);
        pkm.u = __hip_atomic_load(&pk_g[r3 + g_xm], __ATOMIC_RELAXED, AGENT);
    };

    // ---- step 0: xbar = x, q = 0, plain loads from input ----
    step_math(x[g_xp], x[g_xm],
              x[b * PLANE + l_yp], x[b * PLANE + l_ym],
              x[b * PLANE + l_tp], x[b * PLANE + l_tm],
              0.f, 0.f, 0.f);

    pkT pkp, pkm;
    publish(0);
    waitload(0, pkp, pkm);          // halo loads fly across the barrier
    xb_lds[0][tid] = xbv; q1_lds[0][tid] = q1v; q2_lds[0][tid] = q2v;
    __syncthreads();

    for (int s = 1; s < TSTEPS; ++s) {
        const int r1 = (s - 1) & 1;

        const float xbyp = xb_lds[r1][l_yp];
        const float xbym = xb_lds[r1][l_ym];
        const float xbtp = xb_lds[r1][l_tp];
        const float xbtm = xb_lds[r1][l_tm];
        const float q1ym = q1_lds[r1][l_ym];
        const float q2tm = q2_lds[r1][l_tm];

        step_math(pkp.f[0], pkm.f[0], xbyp, xbym, xbtp, xbtm,
                  pkm.f[1], q1ym, q2tm);

        if (s < TSTEPS - 1) {
            publish(s);
            waitload(s, pkp, pkm);  // prefetch next halo before the barrier
            xb_lds[s & 1][tid] = xbv;
            q1_lds[s & 1][tid] = q1v;
            q2_lds[s & 1][tid] = q2v;
            __syncthreads();
        }
    }

    out[idx] = x0v;   // x1 after step 127
}

extern "C" void kernel_launch(void* const* d_in, const int* in_sizes, int n_in,
                              void* d_out, int out_size, void* d_ws, size_t ws_size,
                              hipStream_t stream) {
    const float* x   = (const float*)d_in[0];
    const float* lam = (const float*)d_in[1];
    const float* tau = (const float*)d_in[2];
    const float* sig = (const float*)d_in[3];
    const float* th  = (const float*)d_in[4];
    float* out = (float*)d_out;

    // ws layout: DEPTH*NSITES packed u64 (8 MB), then flags (256*16 * 128B = 512 KB)
    unsigned long long* pk_g = (unsigned long long*)d_ws;
    unsigned* flags = (unsigned*)(pk_g + (size_t)DEPTH * NSITES);

    // ws is poisoned to 0xAA before every timed call: zero the flag block
    hipMemsetAsync(flags, 0, (size_t)NBLK * NWAVE * 32 * sizeof(unsigned), stream);

    void* args[] = {
        (void*)&x, (void*)&lam, (void*)&tau, (void*)&sig, (void*)&th,
        (void*)&pk_g, (void*)&flags, (void*)&out
    };
    hipLaunchCooperativeKernel((const void*)pdhg_persist,
                               dim3(NBLK), dim3(PLANE), args, 0, stream);
}

// Round 6
// 723.546 us; speedup vs baseline: 8.3142x; 8.3142x over previous
//
#include <hip/hip_runtime.h>
#include <math.h>

// (P, C, NX, NY, NT) = (2, 1, 128, 128, 8), T = 128
#define NP     2
#define NXD    128
#define PLANE  1024               // 128y * 8t sites per x-plane
#define NSITES (NP * NXD * PLANE) // 262144
#define NBLK   (NP * NXD)         // 256 blocks, one x-plane each
#define NSUP   64                 // 64 supersteps x 2 steps = 128

#define AGENT __HIP_MEMORY_SCOPE_AGENT

union P2 { float f[2]; unsigned long long u; };

// R3's proven tree barrier: 1 poller/block, s_sleep backoff, 16-block leaves.
__device__ __forceinline__ void gridbar(unsigned* __restrict__ bar, unsigned step) {
    __syncthreads();  // drains each wave's vmcnt: data stores are at the coherence point
    if (threadIdx.x == 0) {
        unsigned* leaf = bar + ((blockIdx.x >> 4) << 4);
        unsigned* root = bar + 512;
        unsigned* flag = bar + 576;
        const unsigned old = __hip_atomic_fetch_add(leaf, 1u, __ATOMIC_RELEASE, AGENT);
        if (old + 1u == 16u * step) {
            const unsigned r = __hip_atomic_fetch_add(root, 1u, __ATOMIC_RELAXED, AGENT);
            if (r + 1u == 16u * step) {
                __hip_atomic_store(flag, step, __ATOMIC_RELAXED, AGENT);
            }
        }
        while (__hip_atomic_load(flag, __ATOMIC_RELAXED, AGENT) < step) {
            __builtin_amdgcn_s_sleep(1);
        }
    }
    __syncthreads();
}

struct St { float x0, p, q0, q1, q2, xb; };

__global__ __launch_bounds__(1024, 4) void pdhg_persist(
    const float* __restrict__ x,
    const float* __restrict__ lam,
    const float* __restrict__ tau_p,
    const float* __restrict__ sigma_p,
    const float* __restrict__ theta_p,
    unsigned long long* __restrict__ pkA,  // 2 slots * NSITES {xbar,q0}
    unsigned long long* __restrict__ pkB,  // 2 slots * NSITES {p,x0}
    unsigned long long* __restrict__ pkC,  // 2 slots * NSITES {q1,q2}
    unsigned* __restrict__ bar,
    float* __restrict__ out)
{
    // Phase-A staging: planes {m1, own, p1} of step-2g xbar/q1/q2 (36 KB)
    __shared__ float A_xb[3][PLANE], A_q1[3][PLANE], A_q2[3][PLANE];
    // Phase-B exchange: own plane's step-(2g+1) xbar/q1/q2 (12 KB)
    __shared__ float B_xb[PLANE], B_q1[PLANE], B_q2[PLANE];

    const int b   = blockIdx.x;     // plane = pp*128 + ix
    const int tid = threadIdx.x;    // y*8 + t
    const int pp  = b >> 7;
    const int ix  = b & 127;
    const int idx = b * PLANE + tid;

    const int b_p1 = (pp << 7) + ((ix + 1) & 127);
    const int b_m1 = (pp << 7) + ((ix + 127) & 127);
    const int b_p2 = (pp << 7) + ((ix + 2) & 127);
    const int b_m2 = (pp << 7) + ((ix + 126) & 127);
    const int g_p1 = b_p1 * PLANE + tid;
    const int g_m1 = b_m1 * PLANE + tid;
    const int g_p2 = b_p2 * PLANE + tid;
    const int g_m2 = b_m2 * PLANE + tid;

    const int t = tid & 7;
    const int l_yp = (tid + 8) & (PLANE - 1);
    const int l_ym = (tid - 8) & (PLANE - 1);
    const int l_tp = (t == 7) ? tid - 7 : tid + 1;
    const int l_tm = (t == 0) ? tid + 7 : tid - 1;

    const float L = 3.605551275463989f;  // sqrt(13)
    const float s_sig = (1.f / (1.f + __expf(-sigma_p[0]))) / L;
    const float s_tau = (1.f / (1.f + __expf(-tau_p[0]))) / L;
    const float s_th  =  1.f / (1.f + __expf(-theta_p[0]));
    const float inv1s = 1.f / (1.f + s_sig);

    const float xn  = x[idx];
    const float xnp = x[g_p1];
    const float xnm = x[g_m1];

    // lambda registers: own + backward-neighbor sets for all 3 computed planes
    const float lamc   = lam[idx];
    const float l_p1c  = lam[g_p1];
    const float l_m1c  = lam[g_m1];
    const float l_m2c  = lam[g_m2];
    const float lymc   = lam[b * PLANE + l_ym];
    const float ltmc   = lam[b * PLANE + l_tm];
    const float l_p1ym = lam[b_p1 * PLANE + l_ym];
    const float l_p1tm = lam[b_p1 * PLANE + l_tm];
    const float l_m1ym = lam[b_m1 * PLANE + l_ym];
    const float l_m1tm = lam[b_m1 * PLANE + l_tm];

    St own = { xn, xn, 0.f, 0.f, 0.f, xn };   // step-0 state

    auto clip = [](float v, float l) { return fmaxf(-l, fminf(l, v)); };
    auto upd = [&](const St& s, float xn_,
                   float xbxp, float xbxm, float xbyp, float xbym,
                   float xbtp, float xbtm,
                   float q0xm, float q1ym, float q2tm,
                   float lc, float lx, float ly, float lt) -> St {
        const float pn  = (s.p + s_sig * (s.xb - xn_)) * inv1s;
        const float q0n = clip(s.q0 + s_sig * (xbxp - s.xb), lc);
        const float q1n = clip(s.q1 + s_sig * (xbyp - s.xb), lc);
        const float q2n = clip(s.q2 + s_sig * (xbtp - s.xb), lc);
        const float q0m = clip(q0xm + s_sig * (s.xb - xbxm), lx);
        const float q1m = clip(q1ym + s_sig * (s.xb - xbym), ly);
        const float q2m = clip(q2tm + s_sig * (s.xb - xbtm), lt);
        const float dv  = (q0m - q0n) + (q1m - q1n) + (q2m - q2n);
        const float x1  = s.x0 - s_tau * (pn + dv);
        return St{ x1, pn, q0n, q1n, q2n, x1 + s_th * (x1 - s.x0) };
    };

    for (int g = 0; g < NSUP; ++g) {
        P2 aP1, aM1, aP2, aM2, bP1, bM1, cP1, cM1;
        if (g == 0) {
            // initial state derivable from input: xbar=x, q=0, p=x0=x
            aP1.f[0] = xnp;      aP1.f[1] = 0.f;
            aM1.f[0] = xnm;      aM1.f[1] = 0.f;
            aP2.f[0] = x[g_p2];  aP2.f[1] = 0.f;
            aM2.f[0] = x[g_m2];  aM2.f[1] = 0.f;
            bP1.f[0] = xnp;      bP1.f[1] = xnp;   // {p, x0}
            bM1.f[0] = xnm;      bM1.f[1] = xnm;
            cP1.u = 0ull;        cM1.u = 0ull;     // {q1, q2}
        } else {
            const size_t sl = (size_t)((g - 1) & 1) * NSITES;
            aP1.u = __hip_atomic_load(&pkA[sl + g_p1], __ATOMIC_RELAXED, AGENT);
            aM1.u = __hip_atomic_load(&pkA[sl + g_m1], __ATOMIC_RELAXED, AGENT);
            aP2.u = __hip_atomic_load(&pkA[sl + g_p2], __ATOMIC_RELAXED, AGENT);
            aM2.u = __hip_atomic_load(&pkA[sl + g_m2], __ATOMIC_RELAXED, AGENT);
            bP1.u = __hip_atomic_load(&pkB[sl + g_p1], __ATOMIC_RELAXED, AGENT);
            bM1.u = __hip_atomic_load(&pkB[sl + g_m1], __ATOMIC_RELAXED, AGENT);
            cP1.u = __hip_atomic_load(&pkC[sl + g_p1], __ATOMIC_RELAXED, AGENT);
            cM1.u = __hip_atomic_load(&pkC[sl + g_m1], __ATOMIC_RELAXED, AGENT);
        }

        // stage step-2g xbar/q1/q2 for planes {m1, own, p1}
        A_xb[1][tid] = own.xb;    A_q1[1][tid] = own.q1;    A_q2[1][tid] = own.q2;
        A_xb[2][tid] = aP1.f[0];  A_q1[2][tid] = cP1.f[0];  A_q2[2][tid] = cP1.f[1];
        A_xb[0][tid] = aM1.f[0];  A_q1[0][tid] = cM1.f[0];  A_q2[0][tid] = cM1.f[1];
        __syncthreads();

        const float xb_old = own.xb, q0_old = own.q0;
        const St sP = { bP1.f[1], bP1.f[0], aP1.f[1], cP1.f[0], cP1.f[1], aP1.f[0] };
        const St sM = { bM1.f[1], bM1.f[0], aM1.f[1], cM1.f[0], cM1.f[1], aM1.f[0] };

        // step 2g+1 on own plane and both halo planes (redundant, bitwise-identical)
        const St nO = upd(own, xn, aP1.f[0], aM1.f[0],
                          A_xb[1][l_yp], A_xb[1][l_ym], A_xb[1][l_tp], A_xb[1][l_tm],
                          aM1.f[1], A_q1[1][l_ym], A_q2[1][l_tm],
                          lamc, l_m1c, lymc, ltmc);
        const St nP = upd(sP, xnp, aP2.f[0], xb_old,
                          A_xb[2][l_yp], A_xb[2][l_ym], A_xb[2][l_tp], A_xb[2][l_tm],
                          q0_old, A_q1[2][l_ym], A_q2[2][l_tm],
                          l_p1c, lamc, l_p1ym, l_p1tm);
        const St nM = upd(sM, xnm, xb_old, aM2.f[0],
                          A_xb[0][l_yp], A_xb[0][l_ym], A_xb[0][l_tp], A_xb[0][l_tm],
                          aM2.f[1], A_q1[0][l_ym], A_q2[0][l_tm],
                          l_m1c, l_m2c, l_m1ym, l_m1tm);

        // exchange own-plane step-(2g+1) y/t-coupled fields
        B_xb[tid] = nO.xb; B_q1[tid] = nO.q1; B_q2[tid] = nO.q2;
        __syncthreads();

        // step 2g+2 on own plane (x-neighbors are in-register from halo states)
        own = upd(nO, xn, nP.xb, nM.xb,
                  B_xb[l_yp], B_xb[l_ym], B_xb[l_tp], B_xb[l_tm],
                  nM.q0, B_q1[l_ym], B_q2[l_tm],
                  lamc, l_m1c, lymc, ltmc);

        if (g < NSUP - 1) {
            const size_t sw = (size_t)(g & 1) * NSITES;
            P2 w;
            w.f[0] = own.xb; w.f[1] = own.q0;
            __hip_atomic_store(&pkA[sw + idx], w.u, __ATOMIC_RELAXED, AGENT);
            w.f[0] = own.p;  w.f[1] = own.x0;
            __hip_atomic_store(&pkB[sw + idx], w.u, __ATOMIC_RELAXED, AGENT);
            w.f[0] = own.q1; w.f[1] = own.q2;
            __hip_atomic_store(&pkC[sw + idx], w.u, __ATOMIC_RELAXED, AGENT);
            gridbar(bar, (unsigned)(g + 1));
        }
    }

    out[idx] = own.x0;   // x1 after 128 steps
}

extern "C" void kernel_launch(void* const* d_in, const int* in_sizes, int n_in,
                              void* d_out, int out_size, void* d_ws, size_t ws_size,
                              hipStream_t stream) {
    const float* x   = (const float*)d_in[0];
    const float* lam = (const float*)d_in[1];
    const float* tau = (const float*)d_in[2];
    const float* sig = (const float*)d_in[3];
    const float* th  = (const float*)d_in[4];
    float* out = (float*)d_out;

    // ws layout: pkA|pkB|pkC each 2*NSITES u64 (4 MB each), then barrier block
    unsigned long long* pkA = (unsigned long long*)d_ws;
    unsigned long long* pkB = pkA + 2 * (size_t)NSITES;
    unsigned long long* pkC = pkB + 2 * (size_t)NSITES;
    unsigned* bar = (unsigned*)(pkC + 2 * (size_t)NSITES);

    // ws is poisoned to 0xAA before every timed call: zero the barrier block
    hipMemsetAsync(bar, 0, 4096, stream);

    void* args[] = {
        (void*)&x, (void*)&lam, (void*)&tau, (void*)&sig, (void*)&th,
        (void*)&pkA, (void*)&pkB, (void*)&pkC, (void*)&bar, (void*)&out
    };
    hipLaunchCooperativeKernel((const void*)pdhg_persist,
                               dim3(NBLK), dim3(PLANE), args, 0, stream);
}